// Round 3
// baseline (269.313 us; speedup 1.0000x reference)
//
#include <hip/hip_runtime.h>

// IPC point-edge barrier energy, MI355X.
// Inputs (setup_inputs order):
//   d_in[0] Uu              float32 [N_VERTS*2]
//   d_in[1] rest_positions  float32 [N_VERTS*2]
//   d_in[2] pair_v          int32   [N_PAIRS]
//   d_in[3] pair_e0         int32   [N_PAIRS]
//   d_in[4] pair_e1         int32   [N_PAIRS]
// Output: scalar float32 barrier energy.
//
// R1: latency theory wrong (HBM 6%, VALU 10%). R2: MLP + nt-index neutral ->
// not latency-bound, not L2-thrash. Revised: L1 fill-BW bound — 25.2M random
// 8B gathers x 128B line fill = 3.2 GB L2->L1 in 119 us = ~27 TB/s ~ L2
// ceiling. R3 experiment: A/B within one bench — nt on the GATHER loads
// (no L1 allocation -> no line fill) on half the pairs vs control half.

constexpr int N_VERTS = 262144;
constexpr int N_PAIRS = 8388608;
constexpr float DHAT2 = 0.05f * 0.05f;       // 0.0025
constexpr float INV_DHAT2 = 1.0f / DHAT2;    // 400
constexpr float EPSF = 1e-12f;

typedef int v4i __attribute__((ext_vector_type(4)));
typedef float v2f __attribute__((ext_vector_type(2)));

// ---------------------------------------------------------------------------
// Kernel A: coords = rest + Uu  (524288 floats = 131072 float4); also zero out.
// ---------------------------------------------------------------------------
__global__ __launch_bounds__(256) void coords_k(const float4* __restrict__ Uu,
                                                const float4* __restrict__ rest,
                                                float4* __restrict__ coords,
                                                float* __restrict__ out,
                                                int out_n) {
    int i = blockIdx.x * blockDim.x + threadIdx.x;
    float4 u = Uu[i];
    float4 r = rest[i];
    coords[i] = make_float4(u.x + r.x, u.y + r.y, u.z + r.z, u.w + r.w);
    if (blockIdx.x == 0 && threadIdx.x < (unsigned)out_n) out[threadIdx.x] = 0.0f;
}

// ---------------------------------------------------------------------------
// Kernel B: per-pair barrier + reduction over quads [0, nquads) of the given
// (pre-offset) index arrays. NT selects non-temporal (no-L1-allocate) gathers.
// ---------------------------------------------------------------------------
template <bool NT>
__global__ __launch_bounds__(256) void pairs_k(const v2f* __restrict__ coords,
                                               const v4i* __restrict__ pv,
                                               const v4i* __restrict__ pe0,
                                               const v4i* __restrict__ pe1,
                                               int nquads,
                                               float* __restrict__ out) {
    float acc = 0.0f;
    const int stride = gridDim.x * blockDim.x;
    const int tid = blockIdx.x * blockDim.x + threadIdx.x;

    for (int q0 = tid; q0 < nquads; q0 += 2 * stride) {
        const int q1 = q0 + stride;
        const bool two = (q1 < nquads);

        v4i v0 = __builtin_nontemporal_load(pv + q0);
        v4i a0 = __builtin_nontemporal_load(pe0 + q0);
        v4i b0 = __builtin_nontemporal_load(pe1 + q0);
        v4i v1 = {}, a1 = {}, b1 = {};
        if (two) {
            v1 = __builtin_nontemporal_load(pv + q1);
            a1 = __builtin_nontemporal_load(pe0 + q1);
            b1 = __builtin_nontemporal_load(pe1 + q1);
        }

        int vi[8] = {v0.x, v0.y, v0.z, v0.w, v1.x, v1.y, v1.z, v1.w};
        int ai[8] = {a0.x, a0.y, a0.z, a0.w, a1.x, a1.y, a1.z, a1.w};
        int bi[8] = {b0.x, b0.y, b0.z, b0.w, b1.x, b1.y, b1.z, b1.w};

        const int np = two ? 8 : 4;

        v2f P[8], A[8], B[8];
#pragma unroll
        for (int k = 0; k < 8; ++k) {
            if (k < np) {
                if (NT) {
                    P[k] = __builtin_nontemporal_load(coords + vi[k]);
                    A[k] = __builtin_nontemporal_load(coords + ai[k]);
                    B[k] = __builtin_nontemporal_load(coords + bi[k]);
                } else {
                    P[k] = coords[vi[k]];
                    A[k] = coords[ai[k]];
                    B[k] = coords[bi[k]];
                }
            }
        }

#pragma unroll
        for (int k = 0; k < 8; ++k) {
            if (k < np) {
                float abx = B[k].x - A[k].x, aby = B[k].y - A[k].y;
                float apx = P[k].x - A[k].x, apy = P[k].y - A[k].y;

                float denom = fmaxf(abx * abx + aby * aby, EPSF);
                float t = (apx * abx + apy * aby) / denom;
                t = fminf(fmaxf(t, 0.0f), 1.0f);

                float dx = apx - t * abx;
                float dy = apy - t * aby;
                float d2 = dx * dx + dy * dy;

                float d2s = fmaxf(d2, EPSF);
                float dm = d2s - DHAT2;
                float term = -(dm * dm) * __logf(d2s * INV_DHAT2);
                acc += (d2 < DHAT2) ? term : 0.0f;
            }
        }
    }

    // wave (64-lane) shuffle reduction
#pragma unroll
    for (int off = 32; off > 0; off >>= 1)
        acc += __shfl_down(acc, off, 64);

    __shared__ float wsum[4];  // 256 threads = 4 waves
    int lane = threadIdx.x & 63;
    int wave = threadIdx.x >> 6;
    if (lane == 0) wsum[wave] = acc;
    __syncthreads();

    if (threadIdx.x == 0) {
        float s = wsum[0] + wsum[1] + wsum[2] + wsum[3];
        atomicAdd(out, s);
    }
}

// ---------------------------------------------------------------------------
extern "C" void kernel_launch(void* const* d_in, const int* in_sizes, int n_in,
                              void* d_out, int out_size, void* d_ws, size_t ws_size,
                              hipStream_t stream) {
    const float* Uu   = (const float*)d_in[0];
    const float* rest = (const float*)d_in[1];
    const int*   pv   = (const int*)d_in[2];
    const int*   pe0  = (const int*)d_in[3];
    const int*   pe1  = (const int*)d_in[4];
    float* out = (float*)d_out;

    float* coords = (float*)d_ws;  // 2 MB: N_VERTS * 2 floats

    // coords = rest + Uu; also zeroes out[] (d_out is poisoned before replay)
    {
        int nvec = (N_VERTS * 2) / 4;  // 131072
        coords_k<<<nvec / 256, 256, 0, stream>>>(
            (const float4*)Uu, (const float4*)rest, (float4*)coords, out, out_size);
    }

    // barrier energy: A/B split. First half with NT gathers, second half plain.
    {
        const int nquads = N_PAIRS / 4;       // 2097152
        const int half = nquads / 2;          // 1048576
        const int blocks = 2048;              // 8 blocks/CU

        pairs_k<true><<<blocks, 256, 0, stream>>>(
            (const v2f*)coords, (const v4i*)pv, (const v4i*)pe0,
            (const v4i*)pe1, half, out);

        pairs_k<false><<<blocks, 256, 0, stream>>>(
            (const v2f*)coords, (const v4i*)(pv + half), (const v4i*)(pe0 + half),
            (const v4i*)(pe1 + half), nquads - half, out);
    }
}

// Round 4
// 231.958 us; speedup vs baseline: 1.1610x; 1.1610x over previous
//
#include <hip/hip_runtime.h>

// IPC point-edge barrier energy, MI355X.
// R1: not HBM-bound (6% peak), not VALU (10%). R2: MLP-neutral -> throughput
// pipe saturated. R3 A/B: NT gathers 1.65x SLOWER (99 vs 60 us/half) ->
// L1-fill-BW theory falsified; plain path is miss-request-rate bound at
// ~2.9 cyc per L1 miss per CU. R4 experiment: split the gather stream across
// BOTH paths (p,a plain + b non-temporal) on half the pairs vs plain control
// half — if the paths are independent queues, mixed half ~45-50 us vs 60.

constexpr int N_VERTS = 262144;
constexpr int N_PAIRS = 8388608;
constexpr float DHAT2 = 0.05f * 0.05f;       // 0.0025
constexpr float INV_DHAT2 = 1.0f / DHAT2;    // 400
constexpr float EPSF = 1e-12f;

typedef int v4i __attribute__((ext_vector_type(4)));
typedef float v2f __attribute__((ext_vector_type(2)));

// ---------------------------------------------------------------------------
// Kernel A: coords = rest + Uu  (524288 floats = 131072 float4); also zero out.
// ---------------------------------------------------------------------------
__global__ __launch_bounds__(256) void coords_k(const float4* __restrict__ Uu,
                                                const float4* __restrict__ rest,
                                                float4* __restrict__ coords,
                                                float* __restrict__ out,
                                                int out_n) {
    int i = blockIdx.x * blockDim.x + threadIdx.x;
    float4 u = Uu[i];
    float4 r = rest[i];
    coords[i] = make_float4(u.x + r.x, u.y + r.y, u.z + r.z, u.w + r.w);
    if (blockIdx.x == 0 && threadIdx.x < (unsigned)out_n) out[threadIdx.x] = 0.0f;
}

// ---------------------------------------------------------------------------
// Kernel B: per-pair barrier + reduction over quads [0, nquads).
// MIX=false: all three gathers via normal (L1-allocating) path.
// MIX=true : p,a normal; b via non-temporal path (1/3 of gather stream
//            diverted to the NT queue to test pipe parallelism).
// ---------------------------------------------------------------------------
template <bool MIX>
__global__ __launch_bounds__(256) void pairs_k(const v2f* __restrict__ coords,
                                               const v4i* __restrict__ pv,
                                               const v4i* __restrict__ pe0,
                                               const v4i* __restrict__ pe1,
                                               int nquads,
                                               float* __restrict__ out) {
    float acc = 0.0f;
    const int stride = gridDim.x * blockDim.x;
    const int tid = blockIdx.x * blockDim.x + threadIdx.x;

    for (int q0 = tid; q0 < nquads; q0 += 2 * stride) {
        const int q1 = q0 + stride;
        const bool two = (q1 < nquads);

        v4i v0 = __builtin_nontemporal_load(pv + q0);
        v4i a0 = __builtin_nontemporal_load(pe0 + q0);
        v4i b0 = __builtin_nontemporal_load(pe1 + q0);
        v4i v1 = {}, a1 = {}, b1 = {};
        if (two) {
            v1 = __builtin_nontemporal_load(pv + q1);
            a1 = __builtin_nontemporal_load(pe0 + q1);
            b1 = __builtin_nontemporal_load(pe1 + q1);
        }

        int vi[8] = {v0.x, v0.y, v0.z, v0.w, v1.x, v1.y, v1.z, v1.w};
        int ai[8] = {a0.x, a0.y, a0.z, a0.w, a1.x, a1.y, a1.z, a1.w};
        int bi[8] = {b0.x, b0.y, b0.z, b0.w, b1.x, b1.y, b1.z, b1.w};

        const int np = two ? 8 : 4;

        v2f P[8], A[8], B[8];
#pragma unroll
        for (int k = 0; k < 8; ++k) {
            if (k < np) {
                P[k] = coords[vi[k]];
                A[k] = coords[ai[k]];
                if (MIX) {
                    B[k] = __builtin_nontemporal_load(coords + bi[k]);
                } else {
                    B[k] = coords[bi[k]];
                }
            }
        }

#pragma unroll
        for (int k = 0; k < 8; ++k) {
            if (k < np) {
                float abx = B[k].x - A[k].x, aby = B[k].y - A[k].y;
                float apx = P[k].x - A[k].x, apy = P[k].y - A[k].y;

                float denom = fmaxf(abx * abx + aby * aby, EPSF);
                float t = (apx * abx + apy * aby) / denom;
                t = fminf(fmaxf(t, 0.0f), 1.0f);

                float dx = apx - t * abx;
                float dy = apy - t * aby;
                float d2 = dx * dx + dy * dy;

                float d2s = fmaxf(d2, EPSF);
                float dm = d2s - DHAT2;
                float term = -(dm * dm) * __logf(d2s * INV_DHAT2);
                acc += (d2 < DHAT2) ? term : 0.0f;
            }
        }
    }

    // wave (64-lane) shuffle reduction
#pragma unroll
    for (int off = 32; off > 0; off >>= 1)
        acc += __shfl_down(acc, off, 64);

    __shared__ float wsum[4];  // 256 threads = 4 waves
    int lane = threadIdx.x & 63;
    int wave = threadIdx.x >> 6;
    if (lane == 0) wsum[wave] = acc;
    __syncthreads();

    if (threadIdx.x == 0) {
        float s = wsum[0] + wsum[1] + wsum[2] + wsum[3];
        atomicAdd(out, s);
    }
}

// ---------------------------------------------------------------------------
extern "C" void kernel_launch(void* const* d_in, const int* in_sizes, int n_in,
                              void* d_out, int out_size, void* d_ws, size_t ws_size,
                              hipStream_t stream) {
    const float* Uu   = (const float*)d_in[0];
    const float* rest = (const float*)d_in[1];
    const int*   pv   = (const int*)d_in[2];
    const int*   pe0  = (const int*)d_in[3];
    const int*   pe1  = (const int*)d_in[4];
    float* out = (float*)d_out;

    float* coords = (float*)d_ws;  // 2 MB: N_VERTS * 2 floats

    // coords = rest + Uu; also zeroes out[] (d_out is poisoned before replay)
    {
        int nvec = (N_VERTS * 2) / 4;  // 131072
        coords_k<<<nvec / 256, 256, 0, stream>>>(
            (const float4*)Uu, (const float4*)rest, (float4*)coords, out, out_size);
    }

    // barrier energy: A/B split. First half MIXED (b-role NT), second plain.
    {
        const int nquads = N_PAIRS / 4;       // 2097152
        const int half = nquads / 2;          // 1048576
        const int blocks = 2048;              // 8 blocks/CU

        pairs_k<true><<<blocks, 256, 0, stream>>>(
            (const v2f*)coords, (const v4i*)pv, (const v4i*)pe0,
            (const v4i*)pe1, half, out);

        pairs_k<false><<<blocks, 256, 0, stream>>>(
            (const v2f*)coords, (const v4i*)(pv + half), (const v4i*)(pe0 + half),
            (const v4i*)(pe1 + half), nquads - half, out);
    }
}

// Round 5
// 226.196 us; speedup vs baseline: 1.1906x; 1.0255x over previous
//
#include <hip/hip_runtime.h>

// IPC point-edge barrier energy, MI355X — FINAL (reverted to best-known).
//
// Bottleneck history:
//  R1: latency theory wrong (HBM 6%, VALU 10%, occupancy insensitive).
//  R2: 2x MLP + nt index loads -> neutral => a throughput pipe is saturated.
//  R3: NT gathers (no L1 alloc) 1.65x SLOWER => not L1-fill-BW bound.
//  R4: mixed plain/NT gather streams serialize => no parallel second path.
// Converged model: L1 miss-slot (MSHR) x L2-hit-latency bound:
//   rate = ~64 slots / ~200 cyc = 0.32 lane-gathers/cyc/CU;
//   measured 25.2M/256CU/119us/2.4GHz = 0.345 /cyc/CU (4% match).
// 25.2M random 8B gathers from the L2-resident 2MB coords table is the
// irreducible request stream (3 independent uniform indices/pair, no reuse;
// screen tables tight enough to reject need >=320KB > LDS). Floor ~= 119 us.
//
// This file: single full-range pairs_k, plain (L1-allocating) gathers,
// nt index loads (streaming), 8 pairs/thread/iter, block reduce + 1 atomic.

constexpr int N_VERTS = 262144;
constexpr int N_PAIRS = 8388608;
constexpr float DHAT2 = 0.05f * 0.05f;       // 0.0025
constexpr float INV_DHAT2 = 1.0f / DHAT2;    // 400
constexpr float EPSF = 1e-12f;

typedef int v4i __attribute__((ext_vector_type(4)));
typedef float v2f __attribute__((ext_vector_type(2)));

// ---------------------------------------------------------------------------
// Kernel A: coords = rest + Uu  (524288 floats = 131072 float4); also zero out.
// ---------------------------------------------------------------------------
__global__ __launch_bounds__(256) void coords_k(const float4* __restrict__ Uu,
                                                const float4* __restrict__ rest,
                                                float4* __restrict__ coords,
                                                float* __restrict__ out,
                                                int out_n) {
    int i = blockIdx.x * blockDim.x + threadIdx.x;
    float4 u = Uu[i];
    float4 r = rest[i];
    coords[i] = make_float4(u.x + r.x, u.y + r.y, u.z + r.z, u.w + r.w);
    if (blockIdx.x == 0 && threadIdx.x < (unsigned)out_n) out[threadIdx.x] = 0.0f;
}

// ---------------------------------------------------------------------------
// Kernel B: per-pair barrier + block reduction. 8 pairs/thread/iter.
// ---------------------------------------------------------------------------
__global__ __launch_bounds__(256) void pairs_k(const v2f* __restrict__ coords,
                                               const v4i* __restrict__ pv,
                                               const v4i* __restrict__ pe0,
                                               const v4i* __restrict__ pe1,
                                               float* __restrict__ out) {
    float acc = 0.0f;
    const int nquads = N_PAIRS / 4;                 // 2097152
    const int stride = gridDim.x * blockDim.x;      // 524288 at 2048x256
    const int tid = blockIdx.x * blockDim.x + threadIdx.x;

    // Exactly 2 iterations at the chosen grid; guards kept for generality.
    for (int q0 = tid; q0 < nquads; q0 += 2 * stride) {
        const int q1 = q0 + stride;
        const bool two = (q1 < nquads);

        // streaming index loads (nt: neutral on perf, avoids L2 pollution)
        v4i v0 = __builtin_nontemporal_load(pv + q0);
        v4i a0 = __builtin_nontemporal_load(pe0 + q0);
        v4i b0 = __builtin_nontemporal_load(pe1 + q0);
        v4i v1 = {}, a1 = {}, b1 = {};
        if (two) {
            v1 = __builtin_nontemporal_load(pv + q1);
            a1 = __builtin_nontemporal_load(pe0 + q1);
            b1 = __builtin_nontemporal_load(pe1 + q1);
        }

        int vi[8] = {v0.x, v0.y, v0.z, v0.w, v1.x, v1.y, v1.z, v1.w};
        int ai[8] = {a0.x, a0.y, a0.z, a0.w, a1.x, a1.y, a1.z, a1.w};
        int bi[8] = {b0.x, b0.y, b0.z, b0.w, b1.x, b1.y, b1.z, b1.w};

        const int np = two ? 8 : 4;

        // issue all gathers first (plain path: L1-allocating — fastest per R3/R4)
        v2f P[8], A[8], B[8];
#pragma unroll
        for (int k = 0; k < 8; ++k) {
            if (k < np) {
                P[k] = coords[vi[k]];
                A[k] = coords[ai[k]];
                B[k] = coords[bi[k]];
            }
        }

#pragma unroll
        for (int k = 0; k < 8; ++k) {
            if (k < np) {
                float abx = B[k].x - A[k].x, aby = B[k].y - A[k].y;
                float apx = P[k].x - A[k].x, apy = P[k].y - A[k].y;

                float denom = fmaxf(abx * abx + aby * aby, EPSF);
                float t = (apx * abx + apy * aby) / denom;
                t = fminf(fmaxf(t, 0.0f), 1.0f);

                float dx = apx - t * abx;
                float dy = apy - t * aby;
                float d2 = dx * dx + dy * dy;

                float d2s = fmaxf(d2, EPSF);
                float dm = d2s - DHAT2;
                float term = -(dm * dm) * __logf(d2s * INV_DHAT2);
                acc += (d2 < DHAT2) ? term : 0.0f;
            }
        }
    }

    // wave (64-lane) shuffle reduction
#pragma unroll
    for (int off = 32; off > 0; off >>= 1)
        acc += __shfl_down(acc, off, 64);

    __shared__ float wsum[4];  // 256 threads = 4 waves
    int lane = threadIdx.x & 63;
    int wave = threadIdx.x >> 6;
    if (lane == 0) wsum[wave] = acc;
    __syncthreads();

    if (threadIdx.x == 0) {
        float s = wsum[0] + wsum[1] + wsum[2] + wsum[3];
        atomicAdd(out, s);
    }
}

// ---------------------------------------------------------------------------
extern "C" void kernel_launch(void* const* d_in, const int* in_sizes, int n_in,
                              void* d_out, int out_size, void* d_ws, size_t ws_size,
                              hipStream_t stream) {
    const float* Uu   = (const float*)d_in[0];
    const float* rest = (const float*)d_in[1];
    const int*   pv   = (const int*)d_in[2];
    const int*   pe0  = (const int*)d_in[3];
    const int*   pe1  = (const int*)d_in[4];
    float* out = (float*)d_out;

    float* coords = (float*)d_ws;  // 2 MB: N_VERTS * 2 floats

    // coords = rest + Uu; also zeroes out[] (d_out is poisoned before replay)
    {
        int nvec = (N_VERTS * 2) / 4;  // 131072
        coords_k<<<nvec / 256, 256, 0, stream>>>(
            (const float4*)Uu, (const float4*)rest, (float4*)coords, out, out_size);
    }

    // barrier energy: single full-range dispatch, 8 blocks/CU.
    {
        const int blocks = 2048;
        pairs_k<<<blocks, 256, 0, stream>>>(
            (const v2f*)coords, (const v4i*)pv, (const v4i*)pe0,
            (const v4i*)pe1, out);
    }
}